// Round 8
// baseline (350.236 us; speedup 1.0000x reference)
//
#include <hip/hip_runtime.h>
#include <math.h>

#define BB   16384
#define OBS  512
#define NE   16
#define ACTD 256
#define TK   4

// ---------------- ws layout (as round 5, proven ≥ 91 MB) ----------------
#define WS_ROWLIST_OFF  ((size_t)64)
#define WS_PROBLIST_OFF (WS_ROWLIST_OFF + (size_t)NE * BB * 4)
#define WS_SLOT_OFF     (WS_PROBLIST_OFF + (size_t)NE * BB * 4)
#define WS_XBF_OFF      (WS_SLOT_OFF + (size_t)NE * BB * 4)
#define WS_WM_OFF       (WS_XBF_OFF + (size_t)BB * OBS * 2)
#define WS_WL_OFF       (WS_WM_OFF + (size_t)NE * ACTD * OBS * 2)
#define WS_PART_OFF     (WS_WL_OFF + (size_t)NE * ACTD * OBS * 2)
#define WS_NEEDED_A2    (WS_PART_OFF + (size_t)2 * BB * TK * ACTD * 2)

typedef __attribute__((ext_vector_type(8))) short short8;
typedef __attribute__((ext_vector_type(4))) float floatx4;

__device__ __forceinline__ ushort f2bf(float f) {
    union { float f; unsigned u; } v; v.f = f;
    unsigned r = v.u + 0x7fffu + ((v.u >> 16) & 1u);
    return (ushort)(r >> 16);
}
__device__ __forceinline__ float bf2f(ushort u) {
    union { unsigned u; float f; } v; v.u = ((unsigned)u) << 16;
    return v.f;
}
// -5 + 3.5*(tanh(v)+1) == -5 + 7/(1+exp(-2v))
__device__ __forceinline__ float lstd_act(float v) {
    return -5.f + 7.f * __builtin_amdgcn_rcpf(1.f + __expf(-2.f * v));
}

// -------------------------------------------------------------------------
// Both weight tensors -> bf16 in ONE launch; also zeroes the 16 counters.
// -------------------------------------------------------------------------
__global__ __launch_bounds__(256) void cvt2_bf16(
    const float* __restrict__ s0, const float* __restrict__ s1,
    ushort* __restrict__ d0, ushort* __restrict__ d1, int n4,
    int* __restrict__ counts)
{
    if (blockIdx.x == 0 && threadIdx.x < NE) counts[threadIdx.x] = 0;
    const int i = blockIdx.x * 256 + threadIdx.x;
    const float4* src = (i < n4) ? ((const float4*)s0 + i) : ((const float4*)s1 + (i - n4));
    ushort4* dst = (i < n4) ? ((ushort4*)d0 + i) : ((ushort4*)d1 + (i - n4));
    float4 v = *src;
    ushort4 o;
    o.x = f2bf(v.x); o.y = f2bf(v.y); o.z = f2bf(v.z); o.w = f2bf(v.w);
    *dst = o;
}

// -------------------------------------------------------------------------
// Router v2: quarter-wave per row (16 rows/block). fp32 routing logic.
// -------------------------------------------------------------------------
__global__ __launch_bounds__(256) void router_kernel(
    const float* __restrict__ x, const float* __restrict__ rw,
    const float* __restrict__ rb,
    int* __restrict__ counts, int* __restrict__ rowlist,
    float* __restrict__ problist, int* __restrict__ slot_of,
    ushort* __restrict__ xbf, int do_aux)
{
    __shared__ float wlds[NE * OBS];
    __shared__ int   lcnt[NE], lbase[NE];
    __shared__ int   s_e[64], s_lpos[64];
    __shared__ float s_p[64];

    const float4* rw4 = (const float4*)rw;
    float4* wl4 = (float4*)wlds;
    #pragma unroll
    for (int i = 0; i < 8; ++i) wl4[threadIdx.x + 256 * i] = rw4[threadIdx.x + 256 * i];
    if (threadIdx.x < NE) lcnt[threadIdx.x] = 0;
    __syncthreads();

    const int wave = threadIdx.x >> 6;
    const int lane = threadIdx.x & 63;
    const int q    = lane >> 4;
    const int i16  = lane & 15;
    const int row  = blockIdx.x * 16 + wave * 4 + q;

    const float4* xr = (const float4*)(x + (size_t)row * OBS);
    float4 xv[8];
    #pragma unroll
    for (int s = 0; s < 8; ++s) xv[s] = xr[s * 16 + i16];

    if (do_aux) {
        ushort4* xo = (ushort4*)(xbf + (size_t)row * OBS);
        #pragma unroll
        for (int s = 0; s < 8; ++s) {
            ushort4 o;
            o.x = f2bf(xv[s].x); o.y = f2bf(xv[s].y);
            o.z = f2bf(xv[s].z); o.w = f2bf(xv[s].w);
            xo[s * 16 + i16] = o;
        }
    }

    float p[NE];
    float m = -1e30f;
    #pragma unroll
    for (int e = 0; e < NE; ++e) {
        const float4* wep = (const float4*)(wlds + e * OBS);
        float d = 0.f;
        #pragma unroll
        for (int s = 0; s < 8; ++s) {
            float4 wv = wep[s * 16 + i16];
            d += xv[s].x * wv.x + xv[s].y * wv.y + xv[s].z * wv.z + xv[s].w * wv.w;
        }
        d += __shfl_xor(d, 1, 64);
        d += __shfl_xor(d, 2, 64);
        d += __shfl_xor(d, 4, 64);
        d += __shfl_xor(d, 8, 64);
        d += rb[e];
        p[e] = d;
        m = fmaxf(m, d);
    }
    float s = 0.f;
    #pragma unroll
    for (int e = 0; e < NE; ++e) { p[e] = __expf(p[e] - m); s += p[e]; }
    const float inv = 1.f / s;
    #pragma unroll
    for (int e = 0; e < NE; ++e) p[e] *= inv;

    int   sel_e[TK];
    float sel_p[TK];
    #pragma unroll
    for (int k = 0; k < TK; ++k) {
        float best = -1.f; int be = 0;
        #pragma unroll
        for (int e = 0; e < NE; ++e)
            if (p[e] > best) { best = p[e]; be = e; }
        sel_e[k] = be; sel_p[k] = best;
        #pragma unroll
        for (int e = 0; e < NE; ++e)
            if (e == be) p[e] = -2.f;
    }
    if (i16 < TK) {
        const int e = sel_e[i16];
        const int lpos = atomicAdd(&lcnt[e], 1);
        const int sid = (wave * 4 + q) * 4 + i16;
        s_e[sid] = e; s_p[sid] = sel_p[i16]; s_lpos[sid] = lpos;
    }
    __syncthreads();
    if (threadIdx.x < NE)
        lbase[threadIdx.x] = atomicAdd(&counts[threadIdx.x], lcnt[threadIdx.x]);
    __syncthreads();
    if (threadIdx.x < 64) {
        const int sid = threadIdx.x;
        const int e   = s_e[sid];
        const int pos = lbase[e] + s_lpos[sid];
        const int grow = blockIdx.x * 16 + (sid >> 2);
        rowlist[e * BB + pos]  = grow;
        problist[e * BB + pos] = s_p[sid];
        if (do_aux) slot_of[e * BB + pos] = grow * TK + (sid & 3);
    }
}

// -------------------------------------------------------------------------
// LDS-free register MFMA GEMM. grid = (256 row-tiles of 64, 16 experts, 4)
//   z bit0: 128-col half, z bit1: plane. Block 64x128, 4 waves 2x2
//   (wave = 32 rows x 64 cols, acc 2x4 floatx4).
// Both x and W are row-major with K contiguous == exact MFMA fragment
// layout, so fragments load DIRECTLY from global (dwordx4, immediate
// offsets off 6 per-lane pointers). NO LDS staging, NO barriers in the
// K-loop -> compiler software-pipelines with fine-grained vmcnt(N).
// -------------------------------------------------------------------------
__global__ __launch_bounds__(256) void moe_gemm_reg(
    const ushort* __restrict__ xbf,
    const ushort* __restrict__ wmean, const ushort* __restrict__ wlstd,
    const float* __restrict__ mean_b, const float* __restrict__ lstd_b,
    const int* __restrict__ counts, const int* __restrict__ rowlist,
    const float* __restrict__ problist, const int* __restrict__ slot_of,
    ushort* __restrict__ partial)
{
    const int e   = blockIdx.y;
    const int cnt = counts[e];
    const int tile0 = blockIdx.x * 64;
    if (tile0 >= cnt) return;

    const int zz    = blockIdx.z;
    const int which = zz >> 1;
    const int ctile = (zz & 1) * 128;
    const ushort* W   = (which ? wlstd : wmean) + (size_t)e * ACTD * OBS;
    const float* bias = (which ? lstd_b : mean_b) + e * ACTD + ctile;
    ushort* Pp = partial + (size_t)which * BB * TK * ACTD;

    __shared__ int   idx_l[64];
    __shared__ float probs_l[64];

    const int tid = threadIdx.x;
    const int l   = tid & 63;
    const int w   = tid >> 6;

    if (tid < 64) {
        const int pos = tile0 + tid;
        const bool v = pos < cnt;
        probs_l[tid] = v ? problist[e * BB + pos] : 0.f;
        idx_l[tid]   = v ? slot_of[e * BB + pos] : -1;
    }
    __syncthreads();

    const int wm  = (w >> 1) * 32;   // row-half of 64
    const int wn  = (w & 1) * 64;    // col-half of 128
    const int rlo = l & 15;
    const int q   = l >> 4;

    // per-lane fragment base pointers (q covers k-chunk q*8 within each 32)
    const ushort* aptr[2];
    #pragma unroll
    for (int mi = 0; mi < 2; ++mi) {
        const int pos  = tile0 + wm + mi * 16 + rlo;
        const int grow = (pos < cnt) ? rowlist[e * BB + pos] : rowlist[e * BB + tile0];
        aptr[mi] = xbf + (size_t)grow * OBS + q * 8;
    }
    const ushort* bptr[4];
    #pragma unroll
    for (int ni = 0; ni < 4; ++ni)
        bptr[ni] = W + (size_t)(ctile + wn + ni * 16 + rlo) * OBS + q * 8;

    floatx4 acc[2][4];
    #pragma unroll
    for (int mi = 0; mi < 2; ++mi)
        #pragma unroll
        for (int ni = 0; ni < 4; ++ni)
            acc[mi][ni] = (floatx4){0.f, 0.f, 0.f, 0.f};

    // K-loop: 16 steps of K=32. Loads use immediate offsets (ks*32 ushorts).
    #pragma unroll
    for (int ks = 0; ks < OBS / 32; ++ks) {
        short8 af[2], bf[4];
        #pragma unroll
        for (int mi = 0; mi < 2; ++mi)
            af[mi] = *(const short8*)(aptr[mi] + ks * 32);
        #pragma unroll
        for (int ni = 0; ni < 4; ++ni)
            bf[ni] = *(const short8*)(bptr[ni] + ks * 32);
        #pragma unroll
        for (int mi = 0; mi < 2; ++mi)
            #pragma unroll
            for (int ni = 0; ni < 4; ++ni)
                acc[mi][ni] = __builtin_amdgcn_mfma_f32_16x16x32_bf16(
                    af[mi], bf[ni], acc[mi][ni], 0, 0, 0);
    }

    // epilogue: non-atomic bf16 partial stores (slot-indexed)
    #pragma unroll
    for (int mi = 0; mi < 2; ++mi) {
        #pragma unroll
        for (int r = 0; r < 4; ++r) {
            const int lrow = wm + mi * 16 + q * 4 + r;
            const int slot = idx_l[lrow];
            if (slot < 0) continue;
            const float pw = probs_l[lrow];
            ushort* orow = Pp + (size_t)slot * ACTD + ctile + wn + rlo;
            #pragma unroll
            for (int ni = 0; ni < 4; ++ni)
                orow[ni * 16] = f2bf(pw * (acc[mi][ni][r] + bias[wn + ni * 16 + rlo]));
        }
    }
}

// -------------------------------------------------------------------------
// Combine: out[r] = sum_k partial[r*4+k]; fast sigmoid-form activation.
// -------------------------------------------------------------------------
__global__ __launch_bounds__(256) void combine_kernel(
    const ushort* __restrict__ partial, float* __restrict__ out)
{
    const int t  = blockIdx.x * 256 + threadIdx.x;
    const int r  = t >> 6;
    const int c4 = (t & 63) * 4;
    const ushort* Pm = partial;
    const ushort* Pl = partial + (size_t)BB * TK * ACTD;

    float m0 = 0.f, m1 = 0.f, m2 = 0.f, m3 = 0.f;
    float l0 = 0.f, l1 = 0.f, l2 = 0.f, l3 = 0.f;
    #pragma unroll
    for (int k = 0; k < TK; ++k) {
        const size_t off = (size_t)(r * TK + k) * ACTD + c4;
        ushort4 vm = *(const ushort4*)(Pm + off);
        ushort4 vl = *(const ushort4*)(Pl + off);
        m0 += bf2f(vm.x); m1 += bf2f(vm.y); m2 += bf2f(vm.z); m3 += bf2f(vm.w);
        l0 += bf2f(vl.x); l1 += bf2f(vl.y); l2 += bf2f(vl.z); l3 += bf2f(vl.w);
    }
    float4 mo = make_float4(m0, m1, m2, m3);
    float4 lo = make_float4(lstd_act(l0), lstd_act(l1), lstd_act(l2), lstd_act(l3));
    *(float4*)(out + (size_t)r * ACTD + c4) = mo;
    *(float4*)(out + (size_t)BB * ACTD + (size_t)r * ACTD + c4) = lo;
}

// -------------------------------------------------------------------------
// Tier B: fp32 expert-grouped GEMM (round-1, proven fallback).
// -------------------------------------------------------------------------
__global__ __launch_bounds__(256) void moe_gemm_f32(
    const float* __restrict__ x,
    const float* __restrict__ mean_w, const float* __restrict__ mean_b,
    const float* __restrict__ lstd_w, const float* __restrict__ lstd_b,
    const int* __restrict__ counts, const int* __restrict__ rowlist,
    const float* __restrict__ problist, float* __restrict__ out)
{
    const int e = blockIdx.y;
    const int cnt = counts[e];
    const int tile0 = blockIdx.x * 32;
    if (tile0 >= cnt) return;

    const int zz    = blockIdx.z;
    const int which = zz >> 1;
    const int ctile = (zz & 1) * 128;
    const float* W    = (which ? lstd_w : mean_w) + (size_t)e * ACTD * OBS;
    const float* bias = (which ? lstd_b : mean_b) + e * ACTD;
    float* outp = out + (size_t)which * BB * ACTD;

    __shared__ float xls[32][32];
    __shared__ float wls[32][128];

    const int sr  = threadIdx.x >> 3;
    const int skq = threadIdx.x & 7;
    int stage_row = -1;
    {
        const int pos = tile0 + sr;
        if (pos < cnt) stage_row = rowlist[e * BB + pos];
    }

    const int r0 = (threadIdx.x >> 5) << 2;
    const int c0 = (threadIdx.x & 31) << 2;

    float acc[4][4] = {};

    for (int kt = 0; kt < OBS; kt += 32) {
        __syncthreads();
        {
            float4 v = make_float4(0.f, 0.f, 0.f, 0.f);
            if (stage_row >= 0)
                v = *(const float4*)(x + (size_t)stage_row * OBS + kt + skq * 4);
            xls[skq * 4 + 0][sr] = v.x;
            xls[skq * 4 + 1][sr] = v.y;
            xls[skq * 4 + 2][sr] = v.z;
            xls[skq * 4 + 3][sr] = v.w;
        }
        #pragma unroll
        for (int j = 0; j < 4; ++j) {
            const int i  = threadIdx.x + 256 * j;
            const int c  = i >> 3;
            const int kq = i & 7;
            float4 v = *(const float4*)(W + (size_t)(ctile + c) * OBS + kt + kq * 4);
            wls[kq * 4 + 0][c] = v.x;
            wls[kq * 4 + 1][c] = v.y;
            wls[kq * 4 + 2][c] = v.z;
            wls[kq * 4 + 3][c] = v.w;
        }
        __syncthreads();

        #pragma unroll
        for (int k = 0; k < 32; ++k) {
            const float4 xa = *(const float4*)&xls[k][r0];
            const float4 wb = *(const float4*)&wls[k][c0];
            const float xv[4] = { xa.x, xa.y, xa.z, xa.w };
            const float wv[4] = { wb.x, wb.y, wb.z, wb.w };
            #pragma unroll
            for (int i = 0; i < 4; ++i)
                #pragma unroll
                for (int j = 0; j < 4; ++j)
                    acc[i][j] = fmaf(xv[i], wv[j], acc[i][j]);
        }
    }

    #pragma unroll
    for (int i = 0; i < 4; ++i) {
        const int pos = tile0 + r0 + i;
        if (pos >= cnt) break;
        const int grow = rowlist[e * BB + pos];
        const float pw = problist[e * BB + pos];
        float* orow = outp + (size_t)grow * ACTD + ctile + c0;
        #pragma unroll
        for (int j = 0; j < 4; ++j)
            atomicAdd(&orow[j], pw * (acc[i][j] + bias[ctile + c0 + j]));
    }
}

__global__ __launch_bounds__(256) void tanh_ep(float* __restrict__ out)
{
    const int i = blockIdx.x * 256 + threadIdx.x;
    float4* p = (float4*)(out + (size_t)BB * ACTD);
    float4 v = p[i];
    v.x = -5.f + 3.5f * (tanhf(v.x) + 1.f);
    v.y = -5.f + 3.5f * (tanhf(v.y) + 1.f);
    v.z = -5.f + 3.5f * (tanhf(v.z) + 1.f);
    v.w = -5.f + 3.5f * (tanhf(v.w) + 1.f);
    p[i] = v;
}

extern "C" void kernel_launch(void* const* d_in, const int* in_sizes, int n_in,
                              void* d_out, int out_size, void* d_ws, size_t ws_size,
                              hipStream_t stream)
{
    const float* x        = (const float*)d_in[0];
    const float* router_w = (const float*)d_in[1];
    const float* router_b = (const float*)d_in[2];
    const float* mean_w   = (const float*)d_in[3];
    const float* mean_b   = (const float*)d_in[4];
    const float* lstd_w   = (const float*)d_in[5];
    const float* lstd_b   = (const float*)d_in[6];

    float* out = (float*)d_out;
    int*    counts   = (int*)d_ws;
    int*    rowlist  = (int*)((char*)d_ws + WS_ROWLIST_OFF);
    float*  problist = (float*)((char*)d_ws + WS_PROBLIST_OFF);
    int*    slot_of  = (int*)((char*)d_ws + WS_SLOT_OFF);
    ushort* xbf      = (ushort*)((char*)d_ws + WS_XBF_OFF);
    ushort* wmbf     = (ushort*)((char*)d_ws + WS_WM_OFF);
    ushort* wlbf     = (ushort*)((char*)d_ws + WS_WL_OFF);
    ushort* partial  = (ushort*)((char*)d_ws + WS_PART_OFF);

    const bool tierA2 = (ws_size >= WS_NEEDED_A2);

    if (tierA2) {
        const int wn4 = NE * ACTD * OBS / 4;
        cvt2_bf16<<<2 * wn4 / 256, 256, 0, stream>>>(mean_w, lstd_w, wmbf, wlbf,
                                                     wn4, counts);

        router_kernel<<<BB / 16, 256, 0, stream>>>(x, router_w, router_b,
                                                   counts, rowlist, problist,
                                                   slot_of, xbf, 1);

        dim3 grid(BB / 64, NE, 4);
        moe_gemm_reg<<<grid, 256, 0, stream>>>(xbf, wmbf, wlbf, mean_b, lstd_b,
                                               counts, rowlist, problist,
                                               slot_of, partial);
        combine_kernel<<<BB * 64 / 256, 256, 0, stream>>>(partial, out);
    } else {
        hipMemsetAsync(d_ws, 0, 64, stream);
        hipMemsetAsync(d_out, 0, (size_t)out_size * sizeof(float), stream);
        router_kernel<<<BB / 16, 256, 0, stream>>>(x, router_w, router_b,
                                                   counts, rowlist, problist,
                                                   (int*)nullptr, (ushort*)nullptr, 0);
        dim3 grid(BB / 32, NE, 4);
        moe_gemm_f32<<<grid, 256, 0, stream>>>(x, mean_w, mean_b, lstd_w, lstd_b,
                                               counts, rowlist, problist, out);
        tanh_ep<<<(BB * ACTD / 4) / 256, 256, 0, stream>>>(out);
    }
}

// Round 9
// 244.170 us; speedup vs baseline: 1.4344x; 1.4344x over previous
//
#include <hip/hip_runtime.h>
#include <math.h>

#define BB   16384
#define OBS  512
#define NE   16
#define ACTD 256
#define TK   4

// ---------------- ws layout (as round 5, proven ≥ 91 MB) ----------------
#define WS_ROWLIST_OFF  ((size_t)64)
#define WS_PROBLIST_OFF (WS_ROWLIST_OFF + (size_t)NE * BB * 4)
#define WS_SLOT_OFF     (WS_PROBLIST_OFF + (size_t)NE * BB * 4)
#define WS_XBF_OFF      (WS_SLOT_OFF + (size_t)NE * BB * 4)
#define WS_WM_OFF       (WS_XBF_OFF + (size_t)BB * OBS * 2)   // 8 MB: swizzled W (both planes)
#define WS_WL_OFF       (WS_WM_OFF + (size_t)NE * ACTD * OBS * 2)
#define WS_PART_OFF     (WS_WL_OFF + (size_t)NE * ACTD * OBS * 2)
#define WS_NEEDED_A2    (WS_PART_OFF + (size_t)2 * BB * TK * ACTD * 2)

typedef __attribute__((ext_vector_type(8))) short short8;
typedef __attribute__((ext_vector_type(4))) float floatx4;

__device__ __forceinline__ ushort f2bf(float f) {
    union { float f; unsigned u; } v; v.f = f;
    unsigned r = v.u + 0x7fffu + ((v.u >> 16) & 1u);
    return (ushort)(r >> 16);
}
__device__ __forceinline__ float bf2f(ushort u) {
    union { unsigned u; float f; } v; v.u = ((unsigned)u) << 16;
    return v.f;
}
// -5 + 3.5*(tanh(v)+1) == -5 + 7/(1+exp(-2v))
__device__ __forceinline__ float lstd_act(float v) {
    return -5.f + 7.f * __builtin_amdgcn_rcpf(1.f + __expf(-2.f * v));
}

// -------------------------------------------------------------------------
// Weights -> bf16 in MFMA-fragment order ("swizzled"): 1 KB block
//   id = ((e*2+p)*16 + kb)*16 + cb   holds W[p,e][cb*16+rlo][kb*32+q*8+j]
//   at lane offset (lane = q*16+rlo)*16B. A wave's B-frag load of block
//   (cb,kb) is then one fully-coalesced 1 KB global_load_dwordx4.
// Also zeroes the 16 expert counters.
// -------------------------------------------------------------------------
__global__ __launch_bounds__(256) void cvt_swz(
    const float* __restrict__ mw, const float* __restrict__ lw,
    ushort* __restrict__ wsw, int* __restrict__ counts)
{
    if (blockIdx.x == 0 && threadIdx.x < NE) counts[threadIdx.x] = 0;
    const int t    = blockIdx.x * 256 + threadIdx.x;   // 512K threads
    const int lane = t & 63;
    const int B    = t >> 6;                           // 1KB block id (0..8191)
    const int cb   = B & 15;
    const int kb   = (B >> 4) & 15;
    const int e2p  = B >> 8;                           // 0..31
    const int p    = e2p & 1, e = e2p >> 1;
    const int rlo  = lane & 15, q = lane >> 4;
    const float* src = (p ? lw : mw)
        + ((size_t)e * ACTD + cb * 16 + rlo) * OBS + kb * 32 + q * 8;
    float4 v0 = *(const float4*)src;
    float4 v1 = *(const float4*)(src + 4);
    short8 o;
    o[0] = (short)f2bf(v0.x); o[1] = (short)f2bf(v0.y);
    o[2] = (short)f2bf(v0.z); o[3] = (short)f2bf(v0.w);
    o[4] = (short)f2bf(v1.x); o[5] = (short)f2bf(v1.y);
    o[6] = (short)f2bf(v1.z); o[7] = (short)f2bf(v1.w);
    *(short8*)(wsw + (size_t)t * 8) = o;
}

// -------------------------------------------------------------------------
// Router v2: quarter-wave per row (16 rows/block). fp32 routing logic.
// -------------------------------------------------------------------------
__global__ __launch_bounds__(256) void router_kernel(
    const float* __restrict__ x, const float* __restrict__ rw,
    const float* __restrict__ rb,
    int* __restrict__ counts, int* __restrict__ rowlist,
    float* __restrict__ problist, int* __restrict__ slot_of,
    ushort* __restrict__ xbf, int do_aux)
{
    __shared__ float wlds[NE * OBS];
    __shared__ int   lcnt[NE], lbase[NE];
    __shared__ int   s_e[64], s_lpos[64];
    __shared__ float s_p[64];

    const float4* rw4 = (const float4*)rw;
    float4* wl4 = (float4*)wlds;
    #pragma unroll
    for (int i = 0; i < 8; ++i) wl4[threadIdx.x + 256 * i] = rw4[threadIdx.x + 256 * i];
    if (threadIdx.x < NE) lcnt[threadIdx.x] = 0;
    __syncthreads();

    const int wave = threadIdx.x >> 6;
    const int lane = threadIdx.x & 63;
    const int q    = lane >> 4;
    const int i16  = lane & 15;
    const int row  = blockIdx.x * 16 + wave * 4 + q;

    const float4* xr = (const float4*)(x + (size_t)row * OBS);
    float4 xv[8];
    #pragma unroll
    for (int s = 0; s < 8; ++s) xv[s] = xr[s * 16 + i16];

    if (do_aux) {
        ushort4* xo = (ushort4*)(xbf + (size_t)row * OBS);
        #pragma unroll
        for (int s = 0; s < 8; ++s) {
            ushort4 o;
            o.x = f2bf(xv[s].x); o.y = f2bf(xv[s].y);
            o.z = f2bf(xv[s].z); o.w = f2bf(xv[s].w);
            xo[s * 16 + i16] = o;
        }
    }

    float p[NE];
    float m = -1e30f;
    #pragma unroll
    for (int e = 0; e < NE; ++e) {
        const float4* wep = (const float4*)(wlds + e * OBS);
        float d = 0.f;
        #pragma unroll
        for (int s = 0; s < 8; ++s) {
            float4 wv = wep[s * 16 + i16];
            d += xv[s].x * wv.x + xv[s].y * wv.y + xv[s].z * wv.z + xv[s].w * wv.w;
        }
        d += __shfl_xor(d, 1, 64);
        d += __shfl_xor(d, 2, 64);
        d += __shfl_xor(d, 4, 64);
        d += __shfl_xor(d, 8, 64);
        d += rb[e];
        p[e] = d;
        m = fmaxf(m, d);
    }
    float s = 0.f;
    #pragma unroll
    for (int e = 0; e < NE; ++e) { p[e] = __expf(p[e] - m); s += p[e]; }
    const float inv = 1.f / s;
    #pragma unroll
    for (int e = 0; e < NE; ++e) p[e] *= inv;

    int   sel_e[TK];
    float sel_p[TK];
    #pragma unroll
    for (int k = 0; k < TK; ++k) {
        float best = -1.f; int be = 0;
        #pragma unroll
        for (int e = 0; e < NE; ++e)
            if (p[e] > best) { best = p[e]; be = e; }
        sel_e[k] = be; sel_p[k] = best;
        #pragma unroll
        for (int e = 0; e < NE; ++e)
            if (e == be) p[e] = -2.f;
    }
    if (i16 < TK) {
        const int e = sel_e[i16];
        const int lpos = atomicAdd(&lcnt[e], 1);
        const int sid = (wave * 4 + q) * 4 + i16;
        s_e[sid] = e; s_p[sid] = sel_p[i16]; s_lpos[sid] = lpos;
    }
    __syncthreads();
    if (threadIdx.x < NE)
        lbase[threadIdx.x] = atomicAdd(&counts[threadIdx.x], lcnt[threadIdx.x]);
    __syncthreads();
    if (threadIdx.x < 64) {
        const int sid = threadIdx.x;
        const int e   = s_e[sid];
        const int pos = lbase[e] + s_lpos[sid];
        const int grow = blockIdx.x * 16 + (sid >> 2);
        rowlist[e * BB + pos]  = grow;
        problist[e * BB + pos] = s_p[sid];
        if (do_aux) slot_of[e * BB + pos] = grow * TK + (sid & 3);
    }
}

// -------------------------------------------------------------------------
// GEMM v3: barrier-free K-loop. grid = 16384 1D blocks:
//   e = j&15 (XCD-pins 2 experts/XCD under j%8 round-robin), rest = j>>4:
//   plane = rest&1, tile0 = (rest>>1)*32  (covers all BB rows; early-exit).
// Block: 32 rows x 256 cols. x-tile (32 rows x full K, 32 KB, XOR-swizzled)
// staged ONCE via DMA + one __syncthreads. Then 16 iters of
// {1 ds_read_b128 (A) + 8 coalesced 1KB B loads (pre-swizzled W) + 8 MFMA}
// with explicit register double-buffering -> fine-grained vmcnt pipelining.
// -------------------------------------------------------------------------
__global__ __launch_bounds__(256) void moe_gemm_v3(
    const ushort* __restrict__ xbf, const ushort* __restrict__ wsw,
    const float* __restrict__ mean_b, const float* __restrict__ lstd_b,
    const int* __restrict__ counts, const int* __restrict__ rowlist,
    const float* __restrict__ problist, const int* __restrict__ slot_of,
    ushort* __restrict__ partial)
{
    const int j     = blockIdx.x;
    const int e     = j & 15;
    const int rest  = j >> 4;
    const int plane = rest & 1;
    const int tile0 = (rest >> 1) * 32;
    const int cnt   = counts[e];
    if (tile0 >= cnt) return;

    const float* bias = (plane ? lstd_b : mean_b) + e * ACTD;
    ushort* Pp = partial + (size_t)plane * BB * TK * ACTD;
    const ushort* wb = wsw + (size_t)(e * 2 + plane) * 16 * 8192; // + kb*8192

    __shared__ __align__(16) ushort xls[32 * 512];   // 32 KB
    __shared__ int   idx_l[32];
    __shared__ float probs_l[32];

    const int tid = threadIdx.x;
    const int l   = tid & 63;
    const int w   = tid >> 6;

    if (tid < 32) {
        const int pos = tile0 + tid;
        const bool v = pos < cnt;
        probs_l[tid] = v ? problist[e * BB + pos] : 0.f;
        idx_l[tid]   = v ? slot_of[e * BB + pos] : -1;
    }

    // stage x-tile: wave w stages rows 8w..8w+7, one 1 KB DMA per row.
    // LDS slot s (= lane) holds global chunk g = (s&56) | ((s&7)^(r&7)).
    #pragma unroll
    for (int i = 0; i < 8; ++i) {
        const int r   = 8 * w + i;
        const int pos = tile0 + r;
        const int grow = (pos < cnt) ? rowlist[e * BB + pos] : rowlist[e * BB + tile0];
        const int g = (l & 56) | ((l & 7) ^ (r & 7));
        __builtin_amdgcn_global_load_lds(
            (const __attribute__((address_space(1))) unsigned int*)(xbf + (size_t)grow * OBS + g * 8),
            (__attribute__((address_space(3))) unsigned int*)(xls + r * 512 + l * 8),
            16, 0, 0);
    }
    __syncthreads();   // single drain+barrier for the whole kernel

    const int wm   = (w >> 1) * 16;   // row-half of 32
    const int wcb0 = (w & 1) * 8;     // col-block base (8 blocks of 16 cols)
    const int rlo  = l & 15;
    const int q    = l >> 4;
    const int r7   = rlo & 7;

    // per-lane B offsets (ushorts) for the 8 col-blocks
    int voff[8];
    #pragma unroll
    for (int ni = 0; ni < 8; ++ni) voff[ni] = (wcb0 + ni) * 512 + l * 8;
    const int abase = (wm + rlo) * 512;   // A row base (ushorts)

    floatx4 acc[8];
    #pragma unroll
    for (int ni = 0; ni < 8; ++ni) acc[ni] = (floatx4){0.f, 0.f, 0.f, 0.f};

    short8 A[2], Bf[2][8];
    // preload ks=0
    {
        const int sl = (0 * 4 + q) ^ r7;
        A[0] = *(const short8*)(xls + abase + sl * 8);
        const ushort* bk = wb;   // kb = 0
        #pragma unroll
        for (int ni = 0; ni < 8; ++ni)
            Bf[0][ni] = *(const short8*)(bk + voff[ni]);
    }
    #pragma unroll
    for (int ks = 0; ks < 16; ++ks) {
        const int cur = ks & 1, nxt = cur ^ 1;
        if (ks < 15) {
            const int sl = ((ks + 1) * 4 + q) ^ r7;
            A[nxt] = *(const short8*)(xls + abase + sl * 8);
            const ushort* bk = wb + (ks + 1) * 8192;
            #pragma unroll
            for (int ni = 0; ni < 8; ++ni)
                Bf[nxt][ni] = *(const short8*)(bk + voff[ni]);
        }
        #pragma unroll
        for (int ni = 0; ni < 8; ++ni)
            acc[ni] = __builtin_amdgcn_mfma_f32_16x16x32_bf16(
                A[cur], Bf[cur][ni], acc[ni], 0, 0, 0);
    }

    // epilogue: non-atomic bf16 partial stores (slot-indexed)
    #pragma unroll
    for (int rr = 0; rr < 4; ++rr) {
        const int lrow = wm + q * 4 + rr;
        const int slot = idx_l[lrow];
        if (slot < 0) continue;
        const float pw = probs_l[lrow];
        ushort* orow = Pp + (size_t)slot * ACTD + wcb0 * 16 + rlo;
        #pragma unroll
        for (int ni = 0; ni < 8; ++ni)
            orow[ni * 16] = f2bf(pw * (acc[ni][rr] + bias[wcb0 * 16 + ni * 16 + rlo]));
    }
}

// -------------------------------------------------------------------------
// Combine: out[r] = sum_k partial[r*4+k]; fast sigmoid-form activation.
// -------------------------------------------------------------------------
__global__ __launch_bounds__(256) void combine_kernel(
    const ushort* __restrict__ partial, float* __restrict__ out)
{
    const int t  = blockIdx.x * 256 + threadIdx.x;
    const int r  = t >> 6;
    const int c4 = (t & 63) * 4;
    const ushort* Pm = partial;
    const ushort* Pl = partial + (size_t)BB * TK * ACTD;

    float m0 = 0.f, m1 = 0.f, m2 = 0.f, m3 = 0.f;
    float l0 = 0.f, l1 = 0.f, l2 = 0.f, l3 = 0.f;
    #pragma unroll
    for (int k = 0; k < TK; ++k) {
        const size_t off = (size_t)(r * TK + k) * ACTD + c4;
        ushort4 vm = *(const ushort4*)(Pm + off);
        ushort4 vl = *(const ushort4*)(Pl + off);
        m0 += bf2f(vm.x); m1 += bf2f(vm.y); m2 += bf2f(vm.z); m3 += bf2f(vm.w);
        l0 += bf2f(vl.x); l1 += bf2f(vl.y); l2 += bf2f(vl.z); l3 += bf2f(vl.w);
    }
    float4 mo = make_float4(m0, m1, m2, m3);
    float4 lo = make_float4(lstd_act(l0), lstd_act(l1), lstd_act(l2), lstd_act(l3));
    *(float4*)(out + (size_t)r * ACTD + c4) = mo;
    *(float4*)(out + (size_t)BB * ACTD + (size_t)r * ACTD + c4) = lo;
}

// -------------------------------------------------------------------------
// Tier B: fp32 expert-grouped GEMM (round-1, proven fallback).
// -------------------------------------------------------------------------
__global__ __launch_bounds__(256) void moe_gemm_f32(
    const float* __restrict__ x,
    const float* __restrict__ mean_w, const float* __restrict__ mean_b,
    const float* __restrict__ lstd_w, const float* __restrict__ lstd_b,
    const int* __restrict__ counts, const int* __restrict__ rowlist,
    const float* __restrict__ problist, float* __restrict__ out)
{
    const int e = blockIdx.y;
    const int cnt = counts[e];
    const int tile0 = blockIdx.x * 32;
    if (tile0 >= cnt) return;

    const int zz    = blockIdx.z;
    const int which = zz >> 1;
    const int ctile = (zz & 1) * 128;
    const float* W    = (which ? lstd_w : mean_w) + (size_t)e * ACTD * OBS;
    const float* bias = (which ? lstd_b : mean_b) + e * ACTD;
    float* outp = out + (size_t)which * BB * ACTD;

    __shared__ float xls[32][32];
    __shared__ float wls[32][128];

    const int sr  = threadIdx.x >> 3;
    const int skq = threadIdx.x & 7;
    int stage_row = -1;
    {
        const int pos = tile0 + sr;
        if (pos < cnt) stage_row = rowlist[e * BB + pos];
    }

    const int r0 = (threadIdx.x >> 5) << 2;
    const int c0 = (threadIdx.x & 31) << 2;

    float acc[4][4] = {};

    for (int kt = 0; kt < OBS; kt += 32) {
        __syncthreads();
        {
            float4 v = make_float4(0.f, 0.f, 0.f, 0.f);
            if (stage_row >= 0)
                v = *(const float4*)(x + (size_t)stage_row * OBS + kt + skq * 4);
            xls[skq * 4 + 0][sr] = v.x;
            xls[skq * 4 + 1][sr] = v.y;
            xls[skq * 4 + 2][sr] = v.z;
            xls[skq * 4 + 3][sr] = v.w;
        }
        #pragma unroll
        for (int jj = 0; jj < 4; ++jj) {
            const int i  = threadIdx.x + 256 * jj;
            const int c  = i >> 3;
            const int kq = i & 7;
            float4 v = *(const float4*)(W + (size_t)(ctile + c) * OBS + kt + kq * 4);
            wls[kq * 4 + 0][c] = v.x;
            wls[kq * 4 + 1][c] = v.y;
            wls[kq * 4 + 2][c] = v.z;
            wls[kq * 4 + 3][c] = v.w;
        }
        __syncthreads();

        #pragma unroll
        for (int k = 0; k < 32; ++k) {
            const float4 xa = *(const float4*)&xls[k][r0];
            const float4 wbv = *(const float4*)&wls[k][c0];
            const float xvv[4] = { xa.x, xa.y, xa.z, xa.w };
            const float wvv[4] = { wbv.x, wbv.y, wbv.z, wbv.w };
            #pragma unroll
            for (int i = 0; i < 4; ++i)
                #pragma unroll
                for (int jj = 0; jj < 4; ++jj)
                    acc[i][jj] = fmaf(xvv[i], wvv[jj], acc[i][jj]);
        }
    }

    #pragma unroll
    for (int i = 0; i < 4; ++i) {
        const int pos = tile0 + r0 + i;
        if (pos >= cnt) break;
        const int grow = rowlist[e * BB + pos];
        const float pw = problist[e * BB + pos];
        float* orow = outp + (size_t)grow * ACTD + ctile + c0;
        #pragma unroll
        for (int jj = 0; jj < 4; ++jj)
            atomicAdd(&orow[jj], pw * (acc[i][jj] + bias[ctile + c0 + jj]));
    }
}

__global__ __launch_bounds__(256) void tanh_ep(float* __restrict__ out)
{
    const int i = blockIdx.x * 256 + threadIdx.x;
    float4* p = (float4*)(out + (size_t)BB * ACTD);
    float4 v = p[i];
    v.x = -5.f + 3.5f * (tanhf(v.x) + 1.f);
    v.y = -5.f + 3.5f * (tanhf(v.y) + 1.f);
    v.z = -5.f + 3.5f * (tanhf(v.z) + 1.f);
    v.w = -5.f + 3.5f * (tanhf(v.w) + 1.f);
    p[i] = v;
}

extern "C" void kernel_launch(void* const* d_in, const int* in_sizes, int n_in,
                              void* d_out, int out_size, void* d_ws, size_t ws_size,
                              hipStream_t stream)
{
    const float* x        = (const float*)d_in[0];
    const float* router_w = (const float*)d_in[1];
    const float* router_b = (const float*)d_in[2];
    const float* mean_w   = (const float*)d_in[3];
    const float* mean_b   = (const float*)d_in[4];
    const float* lstd_w   = (const float*)d_in[5];
    const float* lstd_b   = (const float*)d_in[6];

    float* out = (float*)d_out;
    int*    counts   = (int*)d_ws;
    int*    rowlist  = (int*)((char*)d_ws + WS_ROWLIST_OFF);
    float*  problist = (float*)((char*)d_ws + WS_PROBLIST_OFF);
    int*    slot_of  = (int*)((char*)d_ws + WS_SLOT_OFF);
    ushort* xbf      = (ushort*)((char*)d_ws + WS_XBF_OFF);
    ushort* wsw      = (ushort*)((char*)d_ws + WS_WM_OFF);   // 8 MB swizzled W
    ushort* partial  = (ushort*)((char*)d_ws + WS_PART_OFF);

    const bool tierA2 = (ws_size >= WS_NEEDED_A2);

    if (tierA2) {
        cvt_swz<<<2048, 256, 0, stream>>>(mean_w, lstd_w, wsw, counts);

        router_kernel<<<BB / 16, 256, 0, stream>>>(x, router_w, router_b,
                                                   counts, rowlist, problist,
                                                   slot_of, xbf, 1);

        moe_gemm_v3<<<16384, 256, 0, stream>>>(xbf, wsw, mean_b, lstd_b,
                                               counts, rowlist, problist,
                                               slot_of, partial);
        combine_kernel<<<BB * 64 / 256, 256, 0, stream>>>(partial, out);
    } else {
        hipMemsetAsync(d_ws, 0, 64, stream);
        hipMemsetAsync(d_out, 0, (size_t)out_size * sizeof(float), stream);
        router_kernel<<<BB / 16, 256, 0, stream>>>(x, router_w, router_b,
                                                   counts, rowlist, problist,
                                                   (int*)nullptr, (ushort*)nullptr, 0);
        dim3 grid(BB / 32, NE, 4);
        moe_gemm_f32<<<grid, 256, 0, stream>>>(x, mean_w, mean_b, lstd_w, lstd_b,
                                               counts, rowlist, problist, out);
        tanh_ep<<<(BB * ACTD / 4) / 256, 256, 0, stream>>>(out);
    }
}